// Round 1
// baseline (139.838 us; speedup 1.0000x reference)
//
#include <hip/hip_runtime.h>

// Problem constants
#define B_    4
#define CIN_  64
#define COUT_ 64
#define H_    128
#define W_    128
#define HW_   (H_*W_)
#define K2_   9
#define NOFF_ 18

// padded NHWC fp16 tensor: rows -2..129 (132), cols -3..132 (136), 64 ch
#define PR_   132
#define PC_   136
// x tile in LDS: rows oh-2..oh+2, cols ow0-3..ow0+66
// layout: xt[((row*8 + slot)*TCOLS + col)*8 + (ch&7)], slot = ch>>3
//   -> bank group = (6*slot + col) % 8 : col varies per lane => ~2-way (free)
#define TROWS 5
#define TCOLS 70

typedef _Float16 f16x8 __attribute__((ext_vector_type(8)));  // MFMA A/B frag
typedef float    f32x4 __attribute__((ext_vector_type(4)));  // MFMA C/D

__device__ __forceinline__ f16x8 splat8(float f) {
    _Float16 h = (_Float16)f;
    return (f16x8){h, h, h, h, h, h, h, h};
}

// ---------------------------------------------------------------------------
// x (NCHW fp32) -> hx interior (padded NHWC fp16), fused with:
//   - fp16 weight repack (wt_b, wt_ob), k-contiguous for MFMA A-frags
//   - border-only zero of hx (interior fully overwritten here, borders zeroed)
// Block = (b, y) row; thread = (xpos, c-half). 512 blocks x 256 thr.
// ---------------------------------------------------------------------------
#define NW_B   (COUT_ * 576)                 // 36864 wt_b tasks
#define NW_OB  (32 * 576)                    // 18432 wt_ob tasks
#define NBORD  (4 * 12544)                   // 50176 border 16B segments
__global__ __launch_bounds__(256) void x2h_prep(const float* __restrict__ x,
                                                const float* __restrict__ wd,
                                                const float* __restrict__ wo,
                                                _Float16* __restrict__ hx,
                                                _Float16* __restrict__ wt_b,
                                                _Float16* __restrict__ wt_ob) {
    const int blk = blockIdx.x;          // b*128 + y
    const int b = blk >> 7, y = blk & 127;
    const int xp = threadIdx.x & 127;
    const int ch = threadIdx.x >> 7;     // 0/1 -> channels 0-31 / 32-63
    const float* xs = x + ((b * CIN_ + ch * 32) * H_ + y) * W_ + xp;
    _Float16* hd = hx + (((size_t)b * PR_ + y + 2) * PC_ + xp + 3) * 64 + ch * 32;

    f16x8 h[4];
    #pragma unroll
    for (int j = 0; j < 4; ++j)
        #pragma unroll
        for (int t = 0; t < 8; ++t)
            h[j][t] = (_Float16)xs[(j * 8 + t) * HW_];
    #pragma unroll
    for (int j = 0; j < 4; ++j)
        *(f16x8*)(hd + j * 8) = h[j];

    // ---- side tasks: weight repack + border zeroing (one task per thread) --
    const int gid = blk * 256 + threadIdx.x;
    if (gid < NW_B) {
        int o = gid / 576, rem = gid % 576;
        int k2 = rem >> 6, c = rem & 63;
        wt_b[gid] = (_Float16)wd[(o * CIN_ + c) * K2_ + k2];
    } else if (gid < NW_B + NW_OB) {
        int u = gid - NW_B;
        int oc = u / 576, rem = u % 576;
        int k2 = rem >> 6, c = rem & 63;
        wt_ob[u] = (_Float16)((oc < NOFF_) ? wo[(oc * CIN_ + c) * K2_ + k2] : 0.f);
    } else if (gid < NW_B + NW_OB + NBORD) {
        int s = gid - (NW_B + NW_OB);
        int b2 = s / 12544, u = s % 12544;
        int cs = u & 7, cell = u >> 3;   // 1568 border cells per image
        int r, c;
        if (cell < 544) {                // padded rows {0,1,130,131}, all cols
            int r4 = cell / 136; c = cell % 136;
            r = (r4 < 2) ? r4 : r4 + 128;
        } else {                         // rows 2..129, cols {0,1,2,131..135}
            int c2 = cell - 544;
            r = 2 + (c2 >> 3);
            int c8 = c2 & 7;
            c = (c8 < 3) ? c8 : c8 + 128;
        }
        *(f16x8*)(hx + (((size_t)b2 * PR_ + r) * PC_ + c) * 64 + cs * 8) = splat8(0.f);
    }
}

// ---------------------------------------------------------------------------
// Fused: stage hx tile -> offset conv (f16 MFMA) -> register sampling ->
// deform f16 MFMA. Block = 64 px, 256 thr (4 waves), 3 blocks/CU (44.8 KB).
// Wave cq owns pixels cq*16..cq*16+15 for ALL 64 channels: sampled values are
// the MFMA B-fragments directly -> no vtile, no per-k2 barriers, offsets via
// intra-wave __shfl from the offset-conv accumulators. ONE barrier total.
// ---------------------------------------------------------------------------
__global__ __launch_bounds__(256, 3) void deform_all(const _Float16* __restrict__ hx,
                                                     const _Float16* __restrict__ wt_b,
                                                     const _Float16* __restrict__ wt_ob,
                                                     float* __restrict__ out) {
    __shared__ __align__(16) _Float16 xt[TROWS * 8 * TCOLS * 8];   // 44.8 KB

    const int tid = threadIdx.x;
    int blk = blockIdx.x;
    blk = (blk & 7) * 128 + (blk >> 3);    // XCD swizzle (1024 % 8 == 0, bijective)
    const int b   = blk >> 8;
    const int r2  = blk & 255;
    const int oh  = r2 >> 1;
    const int ow0 = (r2 & 1) << 6;

    // ---- stage x tile: 2800 aligned 16B segments, no bounds checks ----
    const _Float16* hrow = hx + (((size_t)b * PR_ + oh) * PC_ + ow0) * 64;
    for (int i = tid; i < TROWS * TCOLS * 8; i += 256) {
        int r   = i / (TCOLS * 8);
        int rem = i - r * (TCOLS * 8);
        int col = rem >> 3;
        int cs  = rem & 7;                 // channel octet = slot
        f16x8 v = *(const f16x8*)(hrow + ((size_t)r * PC_ + col) * 64 + cs * 8);
        *(f16x8*)&xt[((r * 8 + cs) * TCOLS + col) * 8] = v;
    }
    __syncthreads();                       // the only barrier

    const int lane = tid & 63;
    const int cq   = tid >> 6;             // wave id -> pixel group
    const int quad = lane >> 4;            // channel octet within kb half
    const int nl   = lane & 15;
    const int pix  = cq * 16 + nl;         // this lane's pixel (B-frag column)
    const int ow   = ow0 + pix;

    // ---- offset conv via f16 MFMA: out[32 oc][16 px of this wave], K=576 ----
    f32x4 oacc[2];
    oacc[0] = (f32x4){0.f, 0.f, 0.f, 0.f};
    oacc[1] = (f32x4){0.f, 0.f, 0.f, 0.f};
    #pragma unroll
    for (int t9 = 0; t9 < 9; ++t9) {
        int ky = t9 / 3, kx = t9 - 3 * (t9 / 3);
        #pragma unroll
        for (int kb = 0; kb < 2; ++kb) {
            f16x8 bfr = *(const f16x8*)&xt[((((ky + 1) * 8) + kb * 4 + quad) * TCOLS + pix + kx + 2) * 8];
            #pragma unroll
            for (int mt = 0; mt < 2; ++mt) {
                f16x8 afr = *(const f16x8*)(wt_ob + (mt * 16 + nl) * 576 + t9 * 64 + kb * 32 + quad * 8);
                oacc[mt] = __builtin_amdgcn_mfma_f32_16x16x32_f16(afr, bfr, oacc[mt], 0, 0, 0);
            }
        }
    }
    // oacc[mt][r] holds offset-channel oc = mt*16 + quad*4 + r for pixel cq*16+nl.

    // ---- sampling (registers) + deform MFMA, barrier-free ----
    f32x4 acc[4];
    #pragma unroll
    for (int mb = 0; mb < 4; ++mb) acc[mb] = (f32x4){0.f, 0.f, 0.f, 0.f};

    #pragma unroll
    for (int k2 = 0; k2 < 9; ++k2) {
        // offsets for THIS lane's pixel: oc0=2*k2 (dy), oc0+1 (dx); static src
        const int oc0 = 2 * k2;
        const int mt  = oc0 >> 4;
        const int sq  = (oc0 & 15) >> 2;
        const int r0  = oc0 & 3;           // even -> r0 in {0,2}, dx at r0+1
        float dy = __shfl(oacc[mt][r0],     sq * 16 + nl, 64);
        float dx = __shfl(oacc[mt][r0 + 1], sq * 16 + nl, 64);

        const int ky = k2 / 3, kx = k2 - 3 * (k2 / 3);
        float py = (float)(oh - 1 + ky) + dy;
        float px = (float)(ow - 1 + kx) + dx;
        float y0f = floorf(py), x0f = floorf(px);
        float ly = py - y0f,    lx = px - x0f;
        int   y0 = (int)y0f,    x0 = (int)x0f;
        int   y1 = y0 + 1,      x1 = x0 + 1;

        float wy0 = 1.f - ly, wx0 = 1.f - lx;
        float w00 = wy0 * wx0, w01 = wy0 * lx, w10 = ly * wx0, w11 = ly * lx;

        bool vy0 = (unsigned)y0 < (unsigned)H_;
        bool vy1 = (unsigned)y1 < (unsigned)H_;
        bool vx0 = (unsigned)x0 < (unsigned)W_;
        bool vx1 = (unsigned)x1 < (unsigned)W_;
        if (!(vy0 & vx0)) w00 = 0.f;
        if (!(vy0 & vx1)) w01 = 0.f;
        if (!(vy1 & vx0)) w10 = 0.f;
        if (!(vy1 & vx1)) w11 = 0.f;

        f16x8 W00 = splat8(w00), W01 = splat8(w01), W10 = splat8(w10), W11 = splat8(w11);

        // tile coords (validity needed only when weight != 0)
        int ty0 = y0 - (oh - 2), ty1 = y1 - (oh - 2);
        int tx0 = x0 - (ow0 - 3), tx1 = x1 - (ow0 - 3);
        bool i00 = (unsigned)ty0 < TROWS && (unsigned)tx0 < TCOLS;
        bool i01 = (unsigned)ty0 < TROWS && (unsigned)tx1 < TCOLS;
        bool i10 = (unsigned)ty1 < TROWS && (unsigned)tx0 < TCOLS;
        bool i11 = (unsigned)ty1 < TROWS && (unsigned)tx1 < TCOLS;
        bool ok = (w00 == 0.f || i00) && (w01 == 0.f || i01) &&
                  (w10 == 0.f || i10) && (w11 == 0.f || i11);

        f16x8 v0, v1;   // B-frags: channels quad*8.. (kb0) and 32+quad*8.. (kb1)
        if (ok) {
            int tyc0 = min(max(ty0, 0), TROWS - 1), tyc1 = min(max(ty1, 0), TROWS - 1);
            int txc0 = min(max(tx0, 0), TCOLS - 1), txc1 = min(max(tx1, 0), TCOLS - 1);
            int a00 = ((tyc0 * 8 + quad) * TCOLS + txc0) * 8;
            int a01 = ((tyc0 * 8 + quad) * TCOLS + txc1) * 8;
            int a10 = ((tyc1 * 8 + quad) * TCOLS + txc0) * 8;
            int a11 = ((tyc1 * 8 + quad) * TCOLS + txc1) * 8;
            const int KB1 = 4 * TCOLS * 8;   // slot +4 => channels +32
            f16x8 c00a = *(const f16x8*)&xt[a00], c00b = *(const f16x8*)&xt[a00 + KB1];
            f16x8 c01a = *(const f16x8*)&xt[a01], c01b = *(const f16x8*)&xt[a01 + KB1];
            f16x8 c10a = *(const f16x8*)&xt[a10], c10b = *(const f16x8*)&xt[a10 + KB1];
            f16x8 c11a = *(const f16x8*)&xt[a11], c11b = *(const f16x8*)&xt[a11 + KB1];
            v0 = c00a * W00 + c01a * W01 + c10a * W10 + c11a * W11;
            v1 = c00b * W00 + c01b * W01 + c10b * W10 + c11b * W11;
        } else {
            // rare fallback: image-clamped gather from padded hx
            int y0c = min(max(y0, 0), H_ - 1), y1c = min(max(y1, 0), H_ - 1);
            int x0c = min(max(x0, 0), W_ - 1), x1c = min(max(x1, 0), W_ - 1);
            const _Float16* hb = hx + (size_t)b * PR_ * PC_ * 64 + quad * 8;
            const _Float16* g00 = hb + (((y0c + 2) * PC_) + x0c + 3) * 64;
            const _Float16* g01 = hb + (((y0c + 2) * PC_) + x1c + 3) * 64;
            const _Float16* g10 = hb + (((y1c + 2) * PC_) + x0c + 3) * 64;
            const _Float16* g11 = hb + (((y1c + 2) * PC_) + x1c + 3) * 64;
            v0 = (*(const f16x8*)g00) * W00 + (*(const f16x8*)g01) * W01 +
                 (*(const f16x8*)g10) * W10 + (*(const f16x8*)g11) * W11;
            v1 = (*(const f16x8*)(g00 + 32)) * W00 + (*(const f16x8*)(g01 + 32)) * W01 +
                 (*(const f16x8*)(g10 + 32)) * W10 + (*(const f16x8*)(g11 + 32)) * W11;
        }

        #pragma unroll
        for (int mb = 0; mb < 4; ++mb) {
            f16x8 afr0 = *(const f16x8*)(wt_b + (mb * 16 + nl) * 576 + k2 * 64 + quad * 8);
            acc[mb] = __builtin_amdgcn_mfma_f32_16x16x32_f16(afr0, v0, acc[mb], 0, 0, 0);
            f16x8 afr1 = *(const f16x8*)(wt_b + (mb * 16 + nl) * 576 + k2 * 64 + 32 + quad * 8);
            acc[mb] = __builtin_amdgcn_mfma_f32_16x16x32_f16(afr1, v1, acc[mb], 0, 0, 0);
        }
    }

    // epilogue: C/D col = pixel (nl), row = quad*4 + r (verified layout)
    #pragma unroll
    for (int mb = 0; mb < 4; ++mb)
        #pragma unroll
        for (int r = 0; r < 4; ++r) {
            int o = mb * 16 + quad * 4 + r;
            out[(b * COUT_ + o) * HW_ + oh * W_ + ow0 + pix] = acc[mb][r];
        }
}

// ---------------------------------------------------------------------------
extern "C" void kernel_launch(void* const* d_in, const int* in_sizes, int n_in,
                              void* d_out, int out_size, void* d_ws, size_t ws_size,
                              hipStream_t stream) {
    const float* x        = (const float*)d_in[0];  // (4, 64, 128, 128)
    const float* w_offset = (const float*)d_in[1];  // (18, 64, 3, 3)
    const float* w_deform = (const float*)d_in[2];  // (64, 64, 3, 3)
    float* out = (float*)d_out;                     // (4, 64, 128, 128)

    _Float16* hx    = (_Float16*)d_ws;                        // 4*132*136*64 halfs (9.2 MB)
    _Float16* wt_b  = hx + (size_t)B_ * PR_ * PC_ * 64;       // 64*576
    _Float16* wt_ob = wt_b + (size_t)COUT_ * 576;             // 32*576

    x2h_prep<<<B_ * H_, 256, 0, stream>>>(x, w_deform, w_offset, hx, wt_b, wt_ob);
    deform_all<<<B_ * H_ * (W_ / 64), 256, 0, stream>>>(hx, wt_b, wt_ob, out);
}